// Round 10
// baseline (1091.769 us; speedup 1.0000x reference)
//
#include <hip/hip_runtime.h>

#define N_NODES 500000
#define N_EDGES 8000000
#define W_BKT 1024
#define LOG_W 10
#define NBKT 489                          // dst buckets = ceil(N/1024), also blocks/set
#define NPAD (NBKT * W_BKT)
#define SRC_MASK 0x7FFFFu
#define NRANGE 64                         // src ranges of 8K nodes
#define CHUNK 16384
#define CBLK 512
#define NSEGB 8
#define SEGLENB 62                        // ceil(489/8)

typedef unsigned int uint;

__device__ __forceinline__ float leaky_f(float x) { return x > 0.0f ? x : 0.1f * x; }

// ===========================================================================
// SHARED KERNELS
// ===========================================================================

// k1: H[s][i] = {h0..h4, 0(rd later), 0, 0}  (32B record, single-line gather)
__global__ void k1_hx(const float* __restrict__ x,
                      const float* __restrict__ Wp,
                      const float* __restrict__ Ws,
                      const float* __restrict__ Wv,
                      float* __restrict__ H)
{
    __shared__ float sW[3][25][5];
    int t = threadIdx.x;
    if (t < 125) {
        sW[0][t / 5][t % 5] = Wp[t];
        sW[1][t / 5][t % 5] = Ws[t];
        sW[2][t / 5][t % 5] = Wv[t];
    }
    __syncthreads();
    int i = blockIdx.x * blockDim.x + t;
    if (i >= N_NODES) return;
    float xi[25];
#pragma unroll
    for (int k = 0; k < 25; ++k) xi[k] = x[i * 25 + k];
#pragma unroll
    for (int s = 0; s < 3; ++s) {
        float acc[5] = {0.f, 0.f, 0.f, 0.f, 0.f};
#pragma unroll
        for (int k = 0; k < 25; ++k)
#pragma unroll
            for (int c = 0; c < 5; ++c) acc[c] = fmaf(xi[k], sW[s][k][c], acc[c]);
        float* hp = H + ((size_t)s * N_NODES + i) * 8;
        *(float4*)hp = make_float4(acc[0], acc[1], acc[2], acc[3]);
        *(float4*)(hp + 4) = make_float4(acc[4], 0.f, 0.f, 0.f);
    }
}

// K6: per-node fused MLP epilogue
__global__ void k6_mlp(const float* __restrict__ accum,
                       const float* __restrict__ pw1, const float* __restrict__ pb1,
                       const float* __restrict__ pw2, const float* __restrict__ pb2,
                       const float* __restrict__ cw1, const float* __restrict__ cb1,
                       const float* __restrict__ cw2, const float* __restrict__ cb2,
                       float* __restrict__ out)
{
    __shared__ float sw[257];
    for (int j = threadIdx.x; j < 257; j += blockDim.x) {
        float v;
        if (j < 150) v = pw1[j];
        else if (j < 160) v = pb1[j - 150];
        else if (j < 210) v = pw2[j - 160];
        else if (j < 215) v = pb2[j - 210];
        else if (j < 240) v = cw1[j - 215];
        else if (j < 245) v = cb1[j - 240];
        else if (j < 255) v = cw2[j - 245];
        else v = cb2[j - 255];
        sw[j] = v;
    }
    __syncthreads();
    const float* W1 = sw;         const float* B1 = sw + 150;
    const float* W2 = sw + 160;   const float* B2 = sw + 210;
    const float* C1 = sw + 215;   const float* D1 = sw + 240;
    const float* C2 = sw + 245;   const float* D2 = sw + 255;

    int i = blockIdx.x * blockDim.x + threadIdx.x;
    if (i >= N_NODES) return;

    float hin[15];
#pragma unroll
    for (int s = 0; s < 3; ++s) {
        const float* ap = accum + ((size_t)s * NPAD + i) * 5;
#pragma unroll
        for (int c = 0; c < 5; ++c) hin[s * 5 + c] = leaky_f(ap[c]);
    }
    float h1[10];
#pragma unroll
    for (int o = 0; o < 10; ++o) h1[o] = B1[o];
#pragma unroll
    for (int k = 0; k < 15; ++k)
#pragma unroll
        for (int o = 0; o < 10; ++o) h1[o] = fmaf(hin[k], W1[k * 10 + o], h1[o]);
#pragma unroll
    for (int o = 0; o < 10; ++o) h1[o] = leaky_f(h1[o]);
    float h2[5];
#pragma unroll
    for (int o = 0; o < 5; ++o) h2[o] = B2[o];
#pragma unroll
    for (int k = 0; k < 10; ++k)
#pragma unroll
        for (int o = 0; o < 5; ++o) h2[o] = fmaf(h1[k], W2[k * 5 + o], h2[o]);
    float h3[5];
#pragma unroll
    for (int o = 0; o < 5; ++o) h3[o] = D1[o];
#pragma unroll
    for (int k = 0; k < 5; ++k)
#pragma unroll
        for (int o = 0; o < 5; ++o) h3[o] = fmaf(h2[k], C1[k * 5 + o], h3[o]);
#pragma unroll
    for (int o = 0; o < 5; ++o) h3[o] = leaky_f(h3[o]);
    float o0 = D2[0], o1 = D2[1];
#pragma unroll
    for (int k = 0; k < 5; ++k) {
        o0 = fmaf(h3[k], C2[k * 2 + 0], o0);
        o1 = fmaf(h3[k], C2[k * 2 + 1], o1);
    }
    out[(size_t)i * 2 + 0] = o0;
    out[(size_t)i * 2 + 1] = o1;
}

#define LOADE(j, kk) \
    uint ld##j = (kk) >> 19; \
    const float* hp##j = Hs + (size_t)((kk) & SRC_MASK) * 8; \
    float4 v##j = *(const float4*)hp##j; \
    float e##j = hp##j[4]; \
    float r##j = hp##j[5] * rdd[ld##j];

#define ACCE(j) { \
    float* A = &acc[ld##j * 5]; \
    atomicAdd(A + 0, v##j.x * r##j); \
    atomicAdd(A + 1, v##j.y * r##j); \
    atomicAdd(A + 2, v##j.z * r##j); \
    atomicAdd(A + 3, v##j.w * r##j); \
    atomicAdd(A + 4, e##j * r##j); }

// ===========================================================================
// FAST PATH: two-pass radix sort (pass A: src-range, pass B: dst-bucket)
// ===========================================================================

// PA1: per-block 64-bin histogram of src>>13 (reads src stream only)
__global__ void pA_hist(const int* __restrict__ ep, const int* __restrict__ es,
                        const int* __restrict__ ev, uint* __restrict__ bhA)
{
    int s = blockIdx.y;
    const int* ei = (s == 0) ? ep : ((s == 1) ? es : ev);
    const uint4* s4 = (const uint4*)ei;
    __shared__ uint hist[NRANGE];
    if (threadIdx.x < NRANGE) hist[threadIdx.x] = 0;
    __syncthreads();
    int base4 = blockIdx.x * (CHUNK / 4);
#pragma unroll
    for (int j = 0; j < CHUNK / 4 / CBLK; ++j) {
        int g4 = base4 + j * CBLK + threadIdx.x;
        if (g4 < N_EDGES / 4) {
            uint4 sv = s4[g4];
            atomicAdd(&hist[sv.x >> 13], 1u);
            atomicAdd(&hist[sv.y >> 13], 1u);
            atomicAdd(&hist[sv.z >> 13], 1u);
            atomicAdd(&hist[sv.w >> 13], 1u);
        }
    }
    __syncthreads();
    if (threadIdx.x < NRANGE)
        bhA[((size_t)s * NBKT + blockIdx.x) * NRANGE + threadIdx.x] = hist[threadIdx.x];
}

// PA2: parallel column scan of bhA over blocks (in place), column totals out
__global__ void colScanA(uint* __restrict__ bhA, uint* __restrict__ colTotA)
{
    __shared__ uint buf[512];
    int bin = blockIdx.x, s = blockIdx.y, t = threadIdx.x;
    uint v = (t < NBKT) ? bhA[((size_t)s * NBKT + t) * NRANGE + bin] : 0u;
    buf[t] = v;
    __syncthreads();
    for (int off = 1; off < 512; off <<= 1) {
        uint add = (t >= off) ? buf[t - off] : 0u;
        __syncthreads();
        buf[t] += add;
        __syncthreads();
    }
    if (t < NBKT) bhA[((size_t)s * NBKT + t) * NRANGE + bin] = buf[t] - v;
    if (t == 511) colTotA[s * NRANGE + bin] = buf[511];
}

// PA3: exclusive scan of 64 range totals -> segA[s][0..64] (segA[64]=E)
__global__ void scanTotA(const uint* __restrict__ colTotA, uint* __restrict__ segA)
{
    int s = threadIdx.x;
    if (s < 3) {
        uint run = 0;
        for (int b = 0; b < NRANGE; ++b) {
            segA[s * (NRANGE + 1) + b] = run;
            run += colTotA[s * NRANGE + b];
        }
        segA[s * (NRANGE + 1) + NRANGE] = run;
    }
}

// PA4: scatter into eA grouped by src-range; value packs (dst<<13)|srcLow13
__global__ void pA_scatter(const int* __restrict__ ep, const int* __restrict__ es,
                           const int* __restrict__ ev, const uint* __restrict__ bhA,
                           const uint* __restrict__ segA, uint* __restrict__ eA)
{
    int s = blockIdx.y;
    const int* ei = (s == 0) ? ep : ((s == 1) ? es : ev);
    const uint4* s4 = (const uint4*)ei;
    const uint4* d4 = (const uint4*)((const uint*)ei + N_EDGES);
    uint* eAs = eA + (size_t)s * N_EDGES;
    __shared__ uint cur[NRANGE];
    if (threadIdx.x < NRANGE)
        cur[threadIdx.x] = segA[s * (NRANGE + 1) + threadIdx.x] +
                           bhA[((size_t)s * NBKT + blockIdx.x) * NRANGE + threadIdx.x];
    __syncthreads();
    int base4 = blockIdx.x * (CHUNK / 4);
#pragma unroll
    for (int j = 0; j < CHUNK / 4 / CBLK; ++j) {
        int g4 = base4 + j * CBLK + threadIdx.x;
        if (g4 < N_EDGES / 4) {
            uint4 sv = s4[g4];
            uint4 dv = d4[g4];
            { uint r = atomicAdd(&cur[sv.x >> 13], 1u); eAs[r] = (dv.x << 13) | (sv.x & 8191u); }
            { uint r = atomicAdd(&cur[sv.y >> 13], 1u); eAs[r] = (dv.y << 13) | (sv.y & 8191u); }
            { uint r = atomicAdd(&cur[sv.z >> 13], 1u); eAs[r] = (dv.z << 13) | (sv.z & 8191u); }
            { uint r = atomicAdd(&cur[sv.w >> 13], 1u); eAs[r] = (dv.w << 13) | (sv.w & 8191u); }
        }
    }
}

// PB1: per-block 489-bin histogram of dst-bucket (val>>23)
__global__ void pB_hist(const uint* __restrict__ eA, uint* __restrict__ bhB)
{
    int s = blockIdx.y;
    const uint4* e4 = (const uint4*)(eA + (size_t)s * N_EDGES);
    __shared__ uint hist[NBKT];
    if (threadIdx.x < NBKT) hist[threadIdx.x] = 0;
    __syncthreads();
    int base4 = blockIdx.x * (CHUNK / 4);
#pragma unroll
    for (int j = 0; j < CHUNK / 4 / CBLK; ++j) {
        int g4 = base4 + j * CBLK + threadIdx.x;
        if (g4 < N_EDGES / 4) {
            uint4 v = e4[g4];
            atomicAdd(&hist[v.x >> 23], 1u);
            atomicAdd(&hist[v.y >> 23], 1u);
            atomicAdd(&hist[v.z >> 23], 1u);
            atomicAdd(&hist[v.w >> 23], 1u);
        }
    }
    __syncthreads();
    if (threadIdx.x < NBKT)
        bhB[((size_t)s * NBKT + blockIdx.x) * NBKT + threadIdx.x] = hist[threadIdx.x];
}

// PB2: segmented column scan of bhB (8 segs of 62 blocks), segment totals out
__global__ void kB1_segscan(uint* __restrict__ bhB, uint* __restrict__ segtotB)
{
    int bin = blockIdx.x * 256 + threadIdx.x;
    int seg = blockIdx.y, s = blockIdx.z;
    if (bin >= NBKT) return;
    uint* col = bhB + (size_t)s * NBKT * NBKT + bin;
    int b0 = seg * SEGLENB;
    int b1 = (b0 + SEGLENB < NBKT) ? b0 + SEGLENB : NBKT;
    uint run = 0;
    for (int blk = b0; blk < b1; ++blk) {
        size_t off = (size_t)blk * NBKT;
        uint c = col[off];
        col[off] = run;
        run += c;
    }
    segtotB[((size_t)s * NBKT + bin) * NSEGB + seg] = run;
}

// PB3: per-bucket counts = sum of 8 segment totals
__global__ void kB2_counts(const uint* __restrict__ segtotB, uint* __restrict__ countsB)
{
    int bin = blockIdx.x * 256 + threadIdx.x;
    int s = blockIdx.y;
    if (bin >= NBKT) return;
    const uint4* stp = (const uint4*)(segtotB + ((size_t)s * NBKT + bin) * NSEGB);
    uint4 a = stp[0], b = stp[1];
    countsB[s * NBKT + bin] = a.x + a.y + a.z + a.w + b.x + b.y + b.z + b.w;
}

// PB4: exclusive scan of 489 bucket counts -> baseB/bendB (no padding)
__global__ void scanB(const uint* __restrict__ countsB,
                      uint* __restrict__ baseB, uint* __restrict__ bendB)
{
    __shared__ uint buf[512];
    int s = blockIdx.x, t = threadIdx.x;
    uint v = (t < NBKT) ? countsB[s * NBKT + t] : 0u;
    buf[t] = v;
    __syncthreads();
    for (int off = 1; off < 512; off <<= 1) {
        uint add = (t >= off) ? buf[t - off] : 0u;
        __syncthreads();
        buf[t] += add;
        __syncthreads();
    }
    if (t < NBKT) {
        uint ex = buf[t] - v;
        baseB[s * NBKT + t] = ex;
        bendB[s * NBKT + t] = ex + v;
    }
}

// PB5: segpreB = baseB + cross-segment prefix
__global__ void kB3_segpre(const uint* __restrict__ segtotB,
                           const uint* __restrict__ baseB, uint* __restrict__ segpreB)
{
    int bin = blockIdx.x * 256 + threadIdx.x;
    int s = blockIdx.y;
    if (bin >= NBKT) return;
    uint run = baseB[s * NBKT + bin];
    const uint* st = segtotB + ((size_t)s * NBKT + bin) * NSEGB;
#pragma unroll
    for (int seg = 0; seg < NSEGB; ++seg) {
        segpreB[((size_t)s * NSEGB + seg) * NBKT + bin] = run;
        run += st[seg];
    }
}

// PB6: scatter eA -> parts (packed (local_dst<<19)|src), grouped by dst-bucket,
// src-range order preserved by block ordering. Zero global atomics.
__global__ void pB_scatter(const uint* __restrict__ eA, const uint* __restrict__ bhB,
                           const uint* __restrict__ segpreB, const uint* __restrict__ segA,
                           uint* __restrict__ parts)
{
    int s = blockIdx.y;
    const uint4* e4 = (const uint4*)(eA + (size_t)s * N_EDGES);
    uint* ps = parts + (size_t)s * N_EDGES;
    __shared__ uint hist[NBKT];
    __shared__ uint bbase[NBKT];
    __shared__ uint sStart[NRANGE + 1];
    const uint* bhrow = bhB + ((size_t)s * NBKT + blockIdx.x) * NBKT;
    const uint* segrow = segpreB + ((size_t)s * NSEGB + blockIdx.x / SEGLENB) * NBKT;
    if (threadIdx.x < NBKT) {
        bbase[threadIdx.x] = bhrow[threadIdx.x] + segrow[threadIdx.x];
        hist[threadIdx.x] = 0;
    }
    if (threadIdx.x < NRANGE + 1)
        sStart[threadIdx.x] = segA[s * (NRANGE + 1) + threadIdx.x];
    __syncthreads();
    int base4 = blockIdx.x * (CHUNK / 4);
#pragma unroll
    for (int j = 0; j < CHUNK / 4 / CBLK; ++j) {
        int g4 = base4 + j * CBLK + threadIdx.x;
        if (g4 < N_EDGES / 4) {
            uint4 v = e4[g4];
            uint idx0 = (uint)g4 * 4u;
#pragma unroll
            for (int c = 0; c < 4; ++c) {
                uint val = (c == 0) ? v.x : ((c == 1) ? v.y : ((c == 2) ? v.z : v.w));
                uint idx = idx0 + c;
                uint bkt = val >> 23;
                uint r = atomicAdd(&hist[bkt], 1u);
                uint lo = 0;
#pragma unroll
                for (uint stp = 32; stp > 0; stp >>= 1) {
                    uint m = lo + stp;
                    if (m <= 63u && sStart[m] <= idx) lo = m;
                }
                uint src = (lo << 13) | (val & 8191u);
                ps[bbase[bkt] + r] = (((val >> 13) & 1023u) << 19) | src;
            }
        }
    }
}

// P2a: per-(bucket,set) degree hist -> H slot 5 = rsqrt(1+deg)
__global__ void p2a_deg2(const uint* __restrict__ parts, const uint* __restrict__ baseB,
                         const uint* __restrict__ bendB, float* __restrict__ H)
{
    int b = blockIdx.x, s = blockIdx.y;
    __shared__ uint cnt[W_BKT];
    for (int t = threadIdx.x; t < W_BKT; t += 256) cnt[t] = 0;
    __syncthreads();
    uint st = baseB[s * NBKT + b], en = bendB[s * NBKT + b];
    const uint* pp = parts + (size_t)s * N_EDGES;
    for (uint i = st + threadIdx.x; i < en; i += 256) atomicAdd(&cnt[pp[i] >> 19], 1u);
    __syncthreads();
    int nb = b << LOG_W;
    float* Hs = H + (size_t)s * N_NODES * 8;
    for (int n = threadIdx.x; n < W_BKT; n += 256) {
        int node = nb + n;
        if (node < N_NODES)
            Hs[(size_t)node * 8 + 5] = rsqrtf(1.0f + (float)cnt[n]);
    }
}

// P2b: per-bucket LDS aggregation, ALL THREE SETS in one dispatch
// (blockIdx.y = set) so the grid is 1467 blocks (~5.7/CU) instead of 3x489.
__global__ __launch_bounds__(512, 4) void p2b_agg2(
    const uint* __restrict__ parts, const uint* __restrict__ baseB,
    const uint* __restrict__ bendB, const float* __restrict__ H,
    const float* __restrict__ bp, const float* __restrict__ bs,
    const float* __restrict__ bv, float* __restrict__ accum)
{
    __shared__ float acc[W_BKT * 5];
    __shared__ float rdd[W_BKT];
    __shared__ float sb5[5];
    int b = blockIdx.x, s = blockIdx.y;
    int tid = threadIdx.x;
    const float* bias = (s == 0) ? bp : ((s == 1) ? bs : bv);
    if (tid < 5) sb5[tid] = bias[tid];
    int nb = b << LOG_W;
    const float* Hs = H + (size_t)s * N_NODES * 8;
    __syncthreads();

    for (int n = tid; n < W_BKT; n += 512) {
        int node = nb + n;
        float* a = &acc[n * 5];
        if (node < N_NODES) {
            const float* hp = Hs + (size_t)node * 8;
            float4 v = *(const float4*)hp;
            float h4 = hp[4];
            float rd = hp[5];
            rdd[n] = rd;
            float rr = rd * rd;
            a[0] = fmaf(v.x, rr, sb5[0]);
            a[1] = fmaf(v.y, rr, sb5[1]);
            a[2] = fmaf(v.z, rr, sb5[2]);
            a[3] = fmaf(v.w, rr, sb5[3]);
            a[4] = fmaf(h4, rr, sb5[4]);
        } else {
            rdd[n] = 0.f;
#pragma unroll
            for (int c = 0; c < 5; ++c) a[c] = 0.f;
        }
    }
    __syncthreads();

    uint st = baseB[s * NBKT + b], en = bendB[s * NBKT + b];
    const uint* pp = parts + (size_t)s * N_EDGES;
    uint span = en - st;
    uint nfull = (span / 4096u) * 4096u;
    for (uint i0 = st + tid; i0 < st + nfull; i0 += 4096u) {
        uint k0 = pp[i0];
        uint k1 = pp[i0 + 512];
        uint k2 = pp[i0 + 1024];
        uint k3 = pp[i0 + 1536];
        uint k4 = pp[i0 + 2048];
        uint k5 = pp[i0 + 2560];
        uint k6 = pp[i0 + 3072];
        uint k7 = pp[i0 + 3584];
        LOADE(0, k0) LOADE(1, k1) LOADE(2, k2) LOADE(3, k3)
        LOADE(4, k4) LOADE(5, k5) LOADE(6, k6) LOADE(7, k7)
        ACCE(0) ACCE(1) ACCE(2) ACCE(3) ACCE(4) ACCE(5) ACCE(6) ACCE(7)
    }
    for (uint i = st + nfull + tid; i < en; i += 512u) {
        uint kk = pp[i];
        LOADE(9, kk)
        ACCE(9)
    }
    __syncthreads();

    float* op = accum + ((size_t)s * NPAD + nb) * 5;
    for (int t = tid; t < W_BKT * 5; t += 512) op[t] = acc[t];
}

// ===========================================================================
// FALLBACK PATH (round-0 pipeline, used only if ws too small — needs 66 MB)
// ===========================================================================

__global__ void k1_gemm_deginit(const float* __restrict__ x,
                                const float* __restrict__ Wp,
                                const float* __restrict__ Ws,
                                const float* __restrict__ Wv,
                                float* __restrict__ h, float* __restrict__ deg)
{
    __shared__ float sW[3][25][5];
    int t = threadIdx.x;
    if (t < 125) { sW[0][t/5][t%5]=Wp[t]; sW[1][t/5][t%5]=Ws[t]; sW[2][t/5][t%5]=Wv[t]; }
    __syncthreads();
    for (int i = blockIdx.x * blockDim.x + t; i < N_NODES; i += gridDim.x * blockDim.x) {
        float xi[25];
#pragma unroll
        for (int k = 0; k < 25; ++k) xi[k] = x[i * 25 + k];
#pragma unroll
        for (int s = 0; s < 3; ++s) {
            float acc[5] = {0.f,0.f,0.f,0.f,0.f};
#pragma unroll
            for (int k = 0; k < 25; ++k)
#pragma unroll
                for (int c = 0; c < 5; ++c) acc[c] = fmaf(xi[k], sW[s][k][c], acc[c]);
#pragma unroll
            for (int c = 0; c < 5; ++c) h[(s * N_NODES + i) * 5 + c] = acc[c];
            deg[s * N_NODES + i] = 1.0f;
        }
    }
}

__global__ void k2_degree(const int* __restrict__ ep, const int* __restrict__ es,
                          const int* __restrict__ ev, float* __restrict__ deg)
{
    long e = (long)blockIdx.x * blockDim.x + threadIdx.x;
    if (e >= 3L * N_EDGES) return;
    int s = (int)(e / N_EDGES);
    int i = (int)(e - (long)s * N_EDGES);
    const int* ei = (s == 0) ? ep : ((s == 1) ? es : ev);
    atomicAdd(&deg[s * N_NODES + ei[N_EDGES + i]], 1.0f);
}

__global__ void k3_accum_init(const float* __restrict__ h, const float* __restrict__ deg,
                              const float* __restrict__ bp, const float* __restrict__ bs,
                              const float* __restrict__ bv, float* __restrict__ accum)
{
    int i = blockIdx.x * blockDim.x + threadIdx.x;
    if (i >= N_NODES) return;
#pragma unroll
    for (int s = 0; s < 3; ++s) {
        const float* b = (s == 0) ? bp : ((s == 1) ? bs : bv);
        float inv = 1.0f / deg[s * N_NODES + i];
#pragma unroll
        for (int c = 0; c < 5; ++c)
            accum[(s * N_NODES + i) * 5 + c] = h[(s * N_NODES + i) * 5 + c] * inv + b[c];
    }
}

__global__ void k4_scatter(const int* __restrict__ ep, const int* __restrict__ es,
                           const int* __restrict__ ev, const float* __restrict__ h,
                           const float* __restrict__ deg, float* __restrict__ accum)
{
    long e = (long)blockIdx.x * blockDim.x + threadIdx.x;
    if (e >= 3L * N_EDGES) return;
    int s = (int)(e / N_EDGES);
    int i = (int)(e - (long)s * N_EDGES);
    const int* ei = (s == 0) ? ep : ((s == 1) ? es : ev);
    int src = ei[i];
    int dst = ei[N_EDGES + i];
    float norm = rsqrtf(deg[s * N_NODES + src] * deg[s * N_NODES + dst]);
    const float* hp = h + (size_t)(s * N_NODES + src) * 5;
    float* ap = accum + (size_t)(s * N_NODES + dst) * 5;
#pragma unroll
    for (int c = 0; c < 5; ++c) atomicAdd(&ap[c], hp[c] * norm);
}

__global__ void k5_mlp(const float* __restrict__ accum,
                       const float* __restrict__ pw1, const float* __restrict__ pb1,
                       const float* __restrict__ pw2, const float* __restrict__ pb2,
                       const float* __restrict__ cw1, const float* __restrict__ cb1,
                       const float* __restrict__ cw2, const float* __restrict__ cb2,
                       float* __restrict__ out)
{
    __shared__ float sw[257];
    for (int j = threadIdx.x; j < 257; j += blockDim.x) {
        float v;
        if (j < 150) v = pw1[j];
        else if (j < 160) v = pb1[j - 150];
        else if (j < 210) v = pw2[j - 160];
        else if (j < 215) v = pb2[j - 210];
        else if (j < 240) v = cw1[j - 215];
        else if (j < 245) v = cb1[j - 240];
        else if (j < 255) v = cw2[j - 245];
        else v = cb2[j - 255];
        sw[j] = v;
    }
    __syncthreads();
    const float* W1 = sw; const float* B1 = sw + 150; const float* W2 = sw + 160;
    const float* B2 = sw + 210; const float* C1 = sw + 215; const float* D1 = sw + 240;
    const float* C2 = sw + 245; const float* D2 = sw + 255;
    int i = blockIdx.x * blockDim.x + threadIdx.x;
    if (i >= N_NODES) return;
    float hin[15];
#pragma unroll
    for (int s = 0; s < 3; ++s)
#pragma unroll
        for (int c = 0; c < 5; ++c)
            hin[s * 5 + c] = leaky_f(accum[(size_t)(s * N_NODES + i) * 5 + c]);
    float h1[10];
#pragma unroll
    for (int o = 0; o < 10; ++o) h1[o] = B1[o];
#pragma unroll
    for (int k = 0; k < 15; ++k)
#pragma unroll
        for (int o = 0; o < 10; ++o) h1[o] = fmaf(hin[k], W1[k * 10 + o], h1[o]);
#pragma unroll
    for (int o = 0; o < 10; ++o) h1[o] = leaky_f(h1[o]);
    float h2[5];
#pragma unroll
    for (int o = 0; o < 5; ++o) h2[o] = B2[o];
#pragma unroll
    for (int k = 0; k < 10; ++k)
#pragma unroll
        for (int o = 0; o < 5; ++o) h2[o] = fmaf(h1[k], W2[k * 5 + o], h2[o]);
    float h3[5];
#pragma unroll
    for (int o = 0; o < 5; ++o) h3[o] = D1[o];
#pragma unroll
    for (int k = 0; k < 5; ++k)
#pragma unroll
        for (int o = 0; o < 5; ++o) h3[o] = fmaf(h2[k], C1[k * 5 + o], h3[o]);
#pragma unroll
    for (int o = 0; o < 5; ++o) h3[o] = leaky_f(h3[o]);
    float o0 = D2[0], o1 = D2[1];
#pragma unroll
    for (int k = 0; k < 5; ++k) {
        o0 = fmaf(h3[k], C2[k * 2 + 0], o0);
        o1 = fmaf(h3[k], C2[k * 2 + 1], o1);
    }
    out[(size_t)i * 2 + 0] = o0;
    out[(size_t)i * 2 + 1] = o1;
}

// ===========================================================================

extern "C" void kernel_launch(void* const* d_in, const int* in_sizes, int n_in,
                              void* d_out, int out_size, void* d_ws, size_t ws_size,
                              hipStream_t stream)
{
    const float* x   = (const float*)d_in[0];
    const int*   ep  = (const int*)d_in[1];
    const int*   es  = (const int*)d_in[2];
    const int*   ev  = (const int*)d_in[3];
    const float* Wp  = (const float*)d_in[4];
    const float* bp  = (const float*)d_in[5];
    const float* Ws  = (const float*)d_in[6];
    const float* bs  = (const float*)d_in[7];
    const float* Wv  = (const float*)d_in[8];
    const float* bv  = (const float*)d_in[9];
    const float* pw1 = (const float*)d_in[10];
    const float* pb1 = (const float*)d_in[11];
    const float* pw2 = (const float*)d_in[12];
    const float* pb2 = (const float*)d_in[13];
    const float* cw1 = (const float*)d_in[14];
    const float* cb1 = (const float*)d_in[15];
    const float* cw2 = (const float*)d_in[16];
    const float* cb2 = (const float*)d_in[17];
    float* out = (float*)d_out;

    int gridN = (N_NODES + 255) / 256;

    const size_t H_BYTES    = 3ULL * N_NODES * 8 * 4;        // 48.0 MB
    const size_t P_BYTES    = 3ULL * N_EDGES * 4;            // 96.0 MB (parts)
    const size_t EA_BYTES   = 3ULL * N_EDGES * 4;            // 96.0 MB (eA; accum aliases)
    const size_t BHA_ELEMS  = 3ULL * NBKT * NRANGE;
    const size_t SEGT_ELEMS = 3ULL * NBKT * NSEGB;
    const size_t BHB_ELEMS  = 3ULL * NBKT * NBKT;
    const size_t META2      = (BHA_ELEMS + SEGT_ELEMS + BHB_ELEMS +
                               3 * NRANGE + 3 * (NRANGE + 1) +
                               3ULL * NSEGB * NBKT + 9ULL * NBKT) * 4 + 1024;
    const size_t NEED2 = H_BYTES + P_BYTES + EA_BYTES + META2;

    if (ws_size >= NEED2) {
        float* H      = (float*)d_ws;
        uint*  parts  = (uint*)((char*)d_ws + H_BYTES);
        uint*  eA     = parts + 3ULL * N_EDGES;
        float* accum  = (float*)eA;                     // alias: eA dead before p2b
        uint*  bhA    = eA + 3ULL * N_EDGES;
        uint*  segtotB = bhA + BHA_ELEMS;               // uint4-aligned
        uint*  bhB    = segtotB + SEGT_ELEMS;
        uint*  colTotA = bhB + BHB_ELEMS;
        uint*  segA   = colTotA + 3 * NRANGE;
        uint*  segpreB = segA + 3 * (NRANGE + 1);
        uint*  countsB = segpreB + 3ULL * NSEGB * NBKT;
        uint*  baseB  = countsB + 3 * NBKT;
        uint*  bendB  = baseB + 3 * NBKT;

        dim3 gridP(NBKT, 3);
        dim3 gridCA(NRANGE, 3);
        dim3 gridB1((NBKT + 255) / 256, NSEGB, 3);
        dim3 gridB2((NBKT + 255) / 256, 3);

        k1_hx<<<gridN, 256, 0, stream>>>(x, Wp, Ws, Wv, H);
        pA_hist<<<gridP, CBLK, 0, stream>>>(ep, es, ev, bhA);
        colScanA<<<gridCA, 512, 0, stream>>>(bhA, colTotA);
        scanTotA<<<1, 64, 0, stream>>>(colTotA, segA);
        pA_scatter<<<gridP, CBLK, 0, stream>>>(ep, es, ev, bhA, segA, eA);
        pB_hist<<<gridP, CBLK, 0, stream>>>(eA, bhB);
        kB1_segscan<<<gridB1, 256, 0, stream>>>(bhB, segtotB);
        kB2_counts<<<gridB2, 256, 0, stream>>>(segtotB, countsB);
        scanB<<<3, 512, 0, stream>>>(countsB, baseB, bendB);
        kB3_segpre<<<gridB2, 256, 0, stream>>>(segtotB, baseB, segpreB);
        pB_scatter<<<gridP, CBLK, 0, stream>>>(eA, bhB, segpreB, segA, parts);
        p2a_deg2<<<gridP, 256, 0, stream>>>(parts, baseB, bendB, H);
        // single dispatch, all 3 sets: 1467 blocks (~5.7/CU) for gather concurrency
        p2b_agg2<<<gridP, 512, 0, stream>>>(parts, baseB, bendB, H,
                                            bp, bs, bv, accum);
        k6_mlp<<<gridN, 256, 0, stream>>>(accum, pw1, pb1, pw2, pb2,
                                          cw1, cb1, cw2, cb2, out);
    } else {
        // minimal fallback (round-0 pipeline, needs 66 MB)
        float* ws    = (float*)d_ws;
        float* h     = ws;
        float* deg   = h + 3L * N_NODES * 5;
        float* accum = deg + 3L * N_NODES;

        const int BLK = 256;
        int gridNf = (N_NODES + BLK - 1) / BLK;
        long totalE = 3L * N_EDGES;
        int gridE = (int)((totalE + BLK - 1) / BLK);

        k1_gemm_deginit<<<gridNf, BLK, 0, stream>>>(x, Wp, Ws, Wv, h, deg);
        k2_degree<<<gridE, BLK, 0, stream>>>(ep, es, ev, deg);
        k3_accum_init<<<gridNf, BLK, 0, stream>>>(h, deg, bp, bs, bv, accum);
        k4_scatter<<<gridE, BLK, 0, stream>>>(ep, es, ev, h, deg, accum);
        k5_mlp<<<gridNf, BLK, 0, stream>>>(accum, pw1, pb1, pw2, pb2, cw1, cb1, cw2, cb2, out);
    }
}

// Round 11
// 1082.759 us; speedup vs baseline: 1.0083x; 1.0083x over previous
//
#include <hip/hip_runtime.h>
#include <hip/hip_fp16.h>

#define N_NODES 500000
#define N_EDGES 8000000
#define W_BKT 1024
#define LOG_W 10
#define NBKT 489                          // dst buckets = ceil(N/1024), also blocks/set
#define NPAD (NBKT * W_BKT)
#define SRC_MASK 0x7FFFFu
#define NRANGE 64                         // src ranges of 8K nodes
#define CHUNK 16384
#define CBLK 512
#define NSEGB 8
#define SEGLENB 62                        // ceil(489/8)

typedef unsigned int uint;

__device__ __forceinline__ float leaky_f(float x) { return x > 0.0f ? x : 0.1f * x; }

// ===========================================================================
// SHARED KERNELS
// ===========================================================================

// k1: H[s][i] = {h0..h4, 0(rd later), 0, 0}  (32B record)
__global__ void k1_hx(const float* __restrict__ x,
                      const float* __restrict__ Wp,
                      const float* __restrict__ Ws,
                      const float* __restrict__ Wv,
                      float* __restrict__ H)
{
    __shared__ float sW[3][25][5];
    int t = threadIdx.x;
    if (t < 125) {
        sW[0][t / 5][t % 5] = Wp[t];
        sW[1][t / 5][t % 5] = Ws[t];
        sW[2][t / 5][t % 5] = Wv[t];
    }
    __syncthreads();
    int i = blockIdx.x * blockDim.x + t;
    if (i >= N_NODES) return;
    float xi[25];
#pragma unroll
    for (int k = 0; k < 25; ++k) xi[k] = x[i * 25 + k];
#pragma unroll
    for (int s = 0; s < 3; ++s) {
        float acc[5] = {0.f, 0.f, 0.f, 0.f, 0.f};
#pragma unroll
        for (int k = 0; k < 25; ++k)
#pragma unroll
            for (int c = 0; c < 5; ++c) acc[c] = fmaf(xi[k], sW[s][k][c], acc[c]);
        float* hp = H + ((size_t)s * N_NODES + i) * 8;
        *(float4*)hp = make_float4(acc[0], acc[1], acc[2], acc[3]);
        *(float4*)(hp + 4) = make_float4(acc[4], 0.f, 0.f, 0.f);
    }
}

// K6: per-node fused MLP epilogue
__global__ void k6_mlp(const float* __restrict__ accum,
                       const float* __restrict__ pw1, const float* __restrict__ pb1,
                       const float* __restrict__ pw2, const float* __restrict__ pb2,
                       const float* __restrict__ cw1, const float* __restrict__ cb1,
                       const float* __restrict__ cw2, const float* __restrict__ cb2,
                       float* __restrict__ out)
{
    __shared__ float sw[257];
    for (int j = threadIdx.x; j < 257; j += blockDim.x) {
        float v;
        if (j < 150) v = pw1[j];
        else if (j < 160) v = pb1[j - 150];
        else if (j < 210) v = pw2[j - 160];
        else if (j < 215) v = pb2[j - 210];
        else if (j < 240) v = cw1[j - 215];
        else if (j < 245) v = cb1[j - 240];
        else if (j < 255) v = cw2[j - 245];
        else v = cb2[j - 255];
        sw[j] = v;
    }
    __syncthreads();
    const float* W1 = sw;         const float* B1 = sw + 150;
    const float* W2 = sw + 160;   const float* B2 = sw + 210;
    const float* C1 = sw + 215;   const float* D1 = sw + 240;
    const float* C2 = sw + 245;   const float* D2 = sw + 255;

    int i = blockIdx.x * blockDim.x + threadIdx.x;
    if (i >= N_NODES) return;

    float hin[15];
#pragma unroll
    for (int s = 0; s < 3; ++s) {
        const float* ap = accum + ((size_t)s * NPAD + i) * 5;
#pragma unroll
        for (int c = 0; c < 5; ++c) hin[s * 5 + c] = leaky_f(ap[c]);
    }
    float h1[10];
#pragma unroll
    for (int o = 0; o < 10; ++o) h1[o] = B1[o];
#pragma unroll
    for (int k = 0; k < 15; ++k)
#pragma unroll
        for (int o = 0; o < 10; ++o) h1[o] = fmaf(hin[k], W1[k * 10 + o], h1[o]);
#pragma unroll
    for (int o = 0; o < 10; ++o) h1[o] = leaky_f(h1[o]);
    float h2[5];
#pragma unroll
    for (int o = 0; o < 5; ++o) h2[o] = B2[o];
#pragma unroll
    for (int k = 0; k < 10; ++k)
#pragma unroll
        for (int o = 0; o < 5; ++o) h2[o] = fmaf(h1[k], W2[k * 5 + o], h2[o]);
    float h3[5];
#pragma unroll
    for (int o = 0; o < 5; ++o) h3[o] = D1[o];
#pragma unroll
    for (int k = 0; k < 5; ++k)
#pragma unroll
        for (int o = 0; o < 5; ++o) h3[o] = fmaf(h2[k], C1[k * 5 + o], h3[o]);
#pragma unroll
    for (int o = 0; o < 5; ++o) h3[o] = leaky_f(h3[o]);
    float o0 = D2[0], o1 = D2[1];
#pragma unroll
    for (int k = 0; k < 5; ++k) {
        o0 = fmaf(h3[k], C2[k * 2 + 0], o0);
        o1 = fmaf(h3[k], C2[k * 2 + 1], o1);
    }
    out[(size_t)i * 2 + 0] = o0;
    out[(size_t)i * 2 + 1] = o1;
}

// ===========================================================================
// FAST PATH: two-pass radix sort (pass A: src-range, pass B: dst-bucket)
// ===========================================================================

// PA1: per-block 64-bin histogram of src>>13
__global__ void pA_hist(const int* __restrict__ ep, const int* __restrict__ es,
                        const int* __restrict__ ev, uint* __restrict__ bhA)
{
    int s = blockIdx.y;
    const int* ei = (s == 0) ? ep : ((s == 1) ? es : ev);
    const uint4* s4 = (const uint4*)ei;
    __shared__ uint hist[NRANGE];
    if (threadIdx.x < NRANGE) hist[threadIdx.x] = 0;
    __syncthreads();
    int base4 = blockIdx.x * (CHUNK / 4);
#pragma unroll
    for (int j = 0; j < CHUNK / 4 / CBLK; ++j) {
        int g4 = base4 + j * CBLK + threadIdx.x;
        if (g4 < N_EDGES / 4) {
            uint4 sv = s4[g4];
            atomicAdd(&hist[sv.x >> 13], 1u);
            atomicAdd(&hist[sv.y >> 13], 1u);
            atomicAdd(&hist[sv.z >> 13], 1u);
            atomicAdd(&hist[sv.w >> 13], 1u);
        }
    }
    __syncthreads();
    if (threadIdx.x < NRANGE)
        bhA[((size_t)s * NBKT + blockIdx.x) * NRANGE + threadIdx.x] = hist[threadIdx.x];
}

// PA2: parallel column scan of bhA over blocks (in place), column totals out
__global__ void colScanA(uint* __restrict__ bhA, uint* __restrict__ colTotA)
{
    __shared__ uint buf[512];
    int bin = blockIdx.x, s = blockIdx.y, t = threadIdx.x;
    uint v = (t < NBKT) ? bhA[((size_t)s * NBKT + t) * NRANGE + bin] : 0u;
    buf[t] = v;
    __syncthreads();
    for (int off = 1; off < 512; off <<= 1) {
        uint add = (t >= off) ? buf[t - off] : 0u;
        __syncthreads();
        buf[t] += add;
        __syncthreads();
    }
    if (t < NBKT) bhA[((size_t)s * NBKT + t) * NRANGE + bin] = buf[t] - v;
    if (t == 511) colTotA[s * NRANGE + bin] = buf[511];
}

// PA3: exclusive scan of 64 range totals -> segA[s][0..64]
__global__ void scanTotA(const uint* __restrict__ colTotA, uint* __restrict__ segA)
{
    int s = threadIdx.x;
    if (s < 3) {
        uint run = 0;
        for (int b = 0; b < NRANGE; ++b) {
            segA[s * (NRANGE + 1) + b] = run;
            run += colTotA[s * NRANGE + b];
        }
        segA[s * (NRANGE + 1) + NRANGE] = run;
    }
}

// PA4: scatter into eA grouped by src-range; value packs (dst<<13)|srcLow13
__global__ void pA_scatter(const int* __restrict__ ep, const int* __restrict__ es,
                           const int* __restrict__ ev, const uint* __restrict__ bhA,
                           const uint* __restrict__ segA, uint* __restrict__ eA)
{
    int s = blockIdx.y;
    const int* ei = (s == 0) ? ep : ((s == 1) ? es : ev);
    const uint4* s4 = (const uint4*)ei;
    const uint4* d4 = (const uint4*)((const uint*)ei + N_EDGES);
    uint* eAs = eA + (size_t)s * N_EDGES;
    __shared__ uint cur[NRANGE];
    if (threadIdx.x < NRANGE)
        cur[threadIdx.x] = segA[s * (NRANGE + 1) + threadIdx.x] +
                           bhA[((size_t)s * NBKT + blockIdx.x) * NRANGE + threadIdx.x];
    __syncthreads();
    int base4 = blockIdx.x * (CHUNK / 4);
#pragma unroll
    for (int j = 0; j < CHUNK / 4 / CBLK; ++j) {
        int g4 = base4 + j * CBLK + threadIdx.x;
        if (g4 < N_EDGES / 4) {
            uint4 sv = s4[g4];
            uint4 dv = d4[g4];
            { uint r = atomicAdd(&cur[sv.x >> 13], 1u); eAs[r] = (dv.x << 13) | (sv.x & 8191u); }
            { uint r = atomicAdd(&cur[sv.y >> 13], 1u); eAs[r] = (dv.y << 13) | (sv.y & 8191u); }
            { uint r = atomicAdd(&cur[sv.z >> 13], 1u); eAs[r] = (dv.z << 13) | (sv.z & 8191u); }
            { uint r = atomicAdd(&cur[sv.w >> 13], 1u); eAs[r] = (dv.w << 13) | (sv.w & 8191u); }
        }
    }
}

// PB1: per-block 489-bin histogram of dst-bucket (val>>23)
__global__ void pB_hist(const uint* __restrict__ eA, uint* __restrict__ bhB)
{
    int s = blockIdx.y;
    const uint4* e4 = (const uint4*)(eA + (size_t)s * N_EDGES);
    __shared__ uint hist[NBKT];
    if (threadIdx.x < NBKT) hist[threadIdx.x] = 0;
    __syncthreads();
    int base4 = blockIdx.x * (CHUNK / 4);
#pragma unroll
    for (int j = 0; j < CHUNK / 4 / CBLK; ++j) {
        int g4 = base4 + j * CBLK + threadIdx.x;
        if (g4 < N_EDGES / 4) {
            uint4 v = e4[g4];
            atomicAdd(&hist[v.x >> 23], 1u);
            atomicAdd(&hist[v.y >> 23], 1u);
            atomicAdd(&hist[v.z >> 23], 1u);
            atomicAdd(&hist[v.w >> 23], 1u);
        }
    }
    __syncthreads();
    if (threadIdx.x < NBKT)
        bhB[((size_t)s * NBKT + blockIdx.x) * NBKT + threadIdx.x] = hist[threadIdx.x];
}

// PB2: segmented column scan of bhB (8 segs of 62 blocks), segment totals out
__global__ void kB1_segscan(uint* __restrict__ bhB, uint* __restrict__ segtotB)
{
    int bin = blockIdx.x * 256 + threadIdx.x;
    int seg = blockIdx.y, s = blockIdx.z;
    if (bin >= NBKT) return;
    uint* col = bhB + (size_t)s * NBKT * NBKT + bin;
    int b0 = seg * SEGLENB;
    int b1 = (b0 + SEGLENB < NBKT) ? b0 + SEGLENB : NBKT;
    uint run = 0;
    for (int blk = b0; blk < b1; ++blk) {
        size_t off = (size_t)blk * NBKT;
        uint c = col[off];
        col[off] = run;
        run += c;
    }
    segtotB[((size_t)s * NBKT + bin) * NSEGB + seg] = run;
}

// PB3: per-bucket counts = sum of 8 segment totals
__global__ void kB2_counts(const uint* __restrict__ segtotB, uint* __restrict__ countsB)
{
    int bin = blockIdx.x * 256 + threadIdx.x;
    int s = blockIdx.y;
    if (bin >= NBKT) return;
    const uint4* stp = (const uint4*)(segtotB + ((size_t)s * NBKT + bin) * NSEGB);
    uint4 a = stp[0], b = stp[1];
    countsB[s * NBKT + bin] = a.x + a.y + a.z + a.w + b.x + b.y + b.z + b.w;
}

// PB4: exclusive scan of 489 bucket counts -> baseB/bendB
__global__ void scanB(const uint* __restrict__ countsB,
                      uint* __restrict__ baseB, uint* __restrict__ bendB)
{
    __shared__ uint buf[512];
    int s = blockIdx.x, t = threadIdx.x;
    uint v = (t < NBKT) ? countsB[s * NBKT + t] : 0u;
    buf[t] = v;
    __syncthreads();
    for (int off = 1; off < 512; off <<= 1) {
        uint add = (t >= off) ? buf[t - off] : 0u;
        __syncthreads();
        buf[t] += add;
        __syncthreads();
    }
    if (t < NBKT) {
        uint ex = buf[t] - v;
        baseB[s * NBKT + t] = ex;
        bendB[s * NBKT + t] = ex + v;
    }
}

// PB5: segpreB = baseB + cross-segment prefix
__global__ void kB3_segpre(const uint* __restrict__ segtotB,
                           const uint* __restrict__ baseB, uint* __restrict__ segpreB)
{
    int bin = blockIdx.x * 256 + threadIdx.x;
    int s = blockIdx.y;
    if (bin >= NBKT) return;
    uint run = baseB[s * NBKT + bin];
    const uint* st = segtotB + ((size_t)s * NBKT + bin) * NSEGB;
#pragma unroll
    for (int seg = 0; seg < NSEGB; ++seg) {
        segpreB[((size_t)s * NSEGB + seg) * NBKT + bin] = run;
        run += st[seg];
    }
}

// PB6: scatter eA -> parts (packed (local_dst<<19)|src), dst-bucket grouped,
// src-range order preserved by block ordering. Zero global atomics.
__global__ void pB_scatter(const uint* __restrict__ eA, const uint* __restrict__ bhB,
                           const uint* __restrict__ segpreB, const uint* __restrict__ segA,
                           uint* __restrict__ parts)
{
    int s = blockIdx.y;
    const uint4* e4 = (const uint4*)(eA + (size_t)s * N_EDGES);
    uint* ps = parts + (size_t)s * N_EDGES;
    __shared__ uint hist[NBKT];
    __shared__ uint bbase[NBKT];
    __shared__ uint sStart[NRANGE + 1];
    const uint* bhrow = bhB + ((size_t)s * NBKT + blockIdx.x) * NBKT;
    const uint* segrow = segpreB + ((size_t)s * NSEGB + blockIdx.x / SEGLENB) * NBKT;
    if (threadIdx.x < NBKT) {
        bbase[threadIdx.x] = bhrow[threadIdx.x] + segrow[threadIdx.x];
        hist[threadIdx.x] = 0;
    }
    if (threadIdx.x < NRANGE + 1)
        sStart[threadIdx.x] = segA[s * (NRANGE + 1) + threadIdx.x];
    __syncthreads();
    int base4 = blockIdx.x * (CHUNK / 4);
#pragma unroll
    for (int j = 0; j < CHUNK / 4 / CBLK; ++j) {
        int g4 = base4 + j * CBLK + threadIdx.x;
        if (g4 < N_EDGES / 4) {
            uint4 v = e4[g4];
            uint idx0 = (uint)g4 * 4u;
#pragma unroll
            for (int c = 0; c < 4; ++c) {
                uint val = (c == 0) ? v.x : ((c == 1) ? v.y : ((c == 2) ? v.z : v.w));
                uint idx = idx0 + c;
                uint bkt = val >> 23;
                uint r = atomicAdd(&hist[bkt], 1u);
                uint lo = 0;
#pragma unroll
                for (uint stp = 32; stp > 0; stp >>= 1) {
                    uint m = lo + stp;
                    if (m <= 63u && sStart[m] <= idx) lo = m;
                }
                uint src = (lo << 13) | (val & 8191u);
                ps[bbase[bkt] + r] = (((val >> 13) & 1023u) << 19) | src;
            }
        }
    }
}

// P2a: per-(bucket,set) degree hist -> H slot5 = rd, build fp16 gather record
// G[s][node] = {h0*rd, h1*rd, h2*rd, h3*rd, h4*rd, rd} as 6 halfs in 16B
__global__ void p2a_deg2(const uint* __restrict__ parts, const uint* __restrict__ baseB,
                         const uint* __restrict__ bendB, float* __restrict__ H,
                         uint4* __restrict__ G)
{
    int b = blockIdx.x, s = blockIdx.y;
    __shared__ uint cnt[W_BKT];
    for (int t = threadIdx.x; t < W_BKT; t += 256) cnt[t] = 0;
    __syncthreads();
    uint st = baseB[s * NBKT + b], en = bendB[s * NBKT + b];
    const uint* pp = parts + (size_t)s * N_EDGES;
    for (uint i = st + threadIdx.x; i < en; i += 256) atomicAdd(&cnt[pp[i] >> 19], 1u);
    __syncthreads();
    int nb = b << LOG_W;
    float* Hs = H + (size_t)s * N_NODES * 8;
    uint4* Gs = G + (size_t)s * N_NODES;
    for (int n = threadIdx.x; n < W_BKT; n += 256) {
        int node = nb + n;
        if (node < N_NODES) {
            float rd = rsqrtf(1.0f + (float)cnt[n]);
            float* hp = Hs + (size_t)node * 8;
            hp[5] = rd;
            float4 v = *(const float4*)hp;
            float h4 = hp[4];
            __half2 g01 = __floats2half2_rn(v.x * rd, v.y * rd);
            __half2 g23 = __floats2half2_rn(v.z * rd, v.w * rd);
            __half2 g45 = __floats2half2_rn(h4 * rd, rd);
            uint4 g;
            g.x = *reinterpret_cast<uint*>(&g01);
            g.y = *reinterpret_cast<uint*>(&g23);
            g.z = *reinterpret_cast<uint*>(&g45);
            g.w = 0u;
            Gs[node] = g;
        }
    }
}

#define LOADE(j, kk) \
    uint ld##j = (kk) >> 19; \
    uint4 g##j = Gs[(kk) & SRC_MASK]; \
    float r##j = rdd[ld##j];

#define ACCE(j) { \
    float2 f01 = __half22float2(*reinterpret_cast<const __half2*>(&g##j.x)); \
    float2 f23 = __half22float2(*reinterpret_cast<const __half2*>(&g##j.y)); \
    float2 f45 = __half22float2(*reinterpret_cast<const __half2*>(&g##j.z)); \
    float* A = &acc[ld##j * 5]; \
    atomicAdd(A + 0, f01.x * r##j); \
    atomicAdd(A + 1, f01.y * r##j); \
    atomicAdd(A + 2, f23.x * r##j); \
    atomicAdd(A + 3, f23.y * r##j); \
    atomicAdd(A + 4, f45.x * r##j); }

// P2b: per-bucket LDS aggregation, all 3 sets in one dispatch, 16B fp16 gathers
__global__ __launch_bounds__(512, 4) void p2b_agg2(
    const uint* __restrict__ parts, const uint* __restrict__ baseB,
    const uint* __restrict__ bendB, const float* __restrict__ H,
    const uint4* __restrict__ G,
    const float* __restrict__ bp, const float* __restrict__ bs,
    const float* __restrict__ bv, float* __restrict__ accum)
{
    __shared__ float acc[W_BKT * 5];
    __shared__ float rdd[W_BKT];
    __shared__ float sb5[5];
    int b = blockIdx.x, s = blockIdx.y;
    int tid = threadIdx.x;
    const float* bias = (s == 0) ? bp : ((s == 1) ? bs : bv);
    if (tid < 5) sb5[tid] = bias[tid];
    int nb = b << LOG_W;
    const float* Hs = H + (size_t)s * N_NODES * 8;
    const uint4* Gs = G + (size_t)s * N_NODES;
    __syncthreads();

    // self-loop + bias init from fp32 H: acc = h*rd^2 + bias
    for (int n = tid; n < W_BKT; n += 512) {
        int node = nb + n;
        float* a = &acc[n * 5];
        if (node < N_NODES) {
            const float* hp = Hs + (size_t)node * 8;
            float4 v = *(const float4*)hp;
            float h4 = hp[4];
            float rd = hp[5];
            rdd[n] = rd;
            float rr = rd * rd;
            a[0] = fmaf(v.x, rr, sb5[0]);
            a[1] = fmaf(v.y, rr, sb5[1]);
            a[2] = fmaf(v.z, rr, sb5[2]);
            a[3] = fmaf(v.w, rr, sb5[3]);
            a[4] = fmaf(h4, rr, sb5[4]);
        } else {
            rdd[n] = 0.f;
#pragma unroll
            for (int c = 0; c < 5; ++c) a[c] = 0.f;
        }
    }
    __syncthreads();

    uint st = baseB[s * NBKT + b], en = bendB[s * NBKT + b];
    const uint* pp = parts + (size_t)s * N_EDGES;
    uint span = en - st;
    uint nfull = (span / 4096u) * 4096u;
    for (uint i0 = st + tid; i0 < st + nfull; i0 += 4096u) {
        uint k0 = pp[i0];
        uint k1 = pp[i0 + 512];
        uint k2 = pp[i0 + 1024];
        uint k3 = pp[i0 + 1536];
        uint k4 = pp[i0 + 2048];
        uint k5 = pp[i0 + 2560];
        uint k6 = pp[i0 + 3072];
        uint k7 = pp[i0 + 3584];
        LOADE(0, k0) LOADE(1, k1) LOADE(2, k2) LOADE(3, k3)
        LOADE(4, k4) LOADE(5, k5) LOADE(6, k6) LOADE(7, k7)
        ACCE(0) ACCE(1) ACCE(2) ACCE(3) ACCE(4) ACCE(5) ACCE(6) ACCE(7)
    }
    for (uint i = st + nfull + tid; i < en; i += 512u) {
        uint kk = pp[i];
        LOADE(9, kk)
        ACCE(9)
    }
    __syncthreads();

    float* op = accum + ((size_t)s * NPAD + nb) * 5;
    for (int t = tid; t < W_BKT * 5; t += 512) op[t] = acc[t];
}

// ===========================================================================
// FALLBACK PATH (round-0 pipeline, used only if ws too small — needs 66 MB)
// ===========================================================================

__global__ void k1_gemm_deginit(const float* __restrict__ x,
                                const float* __restrict__ Wp,
                                const float* __restrict__ Ws,
                                const float* __restrict__ Wv,
                                float* __restrict__ h, float* __restrict__ deg)
{
    __shared__ float sW[3][25][5];
    int t = threadIdx.x;
    if (t < 125) { sW[0][t/5][t%5]=Wp[t]; sW[1][t/5][t%5]=Ws[t]; sW[2][t/5][t%5]=Wv[t]; }
    __syncthreads();
    for (int i = blockIdx.x * blockDim.x + t; i < N_NODES; i += gridDim.x * blockDim.x) {
        float xi[25];
#pragma unroll
        for (int k = 0; k < 25; ++k) xi[k] = x[i * 25 + k];
#pragma unroll
        for (int s = 0; s < 3; ++s) {
            float acc[5] = {0.f,0.f,0.f,0.f,0.f};
#pragma unroll
            for (int k = 0; k < 25; ++k)
#pragma unroll
                for (int c = 0; c < 5; ++c) acc[c] = fmaf(xi[k], sW[s][k][c], acc[c]);
#pragma unroll
            for (int c = 0; c < 5; ++c) h[(s * N_NODES + i) * 5 + c] = acc[c];
            deg[s * N_NODES + i] = 1.0f;
        }
    }
}

__global__ void k2_degree(const int* __restrict__ ep, const int* __restrict__ es,
                          const int* __restrict__ ev, float* __restrict__ deg)
{
    long e = (long)blockIdx.x * blockDim.x + threadIdx.x;
    if (e >= 3L * N_EDGES) return;
    int s = (int)(e / N_EDGES);
    int i = (int)(e - (long)s * N_EDGES);
    const int* ei = (s == 0) ? ep : ((s == 1) ? es : ev);
    atomicAdd(&deg[s * N_NODES + ei[N_EDGES + i]], 1.0f);
}

__global__ void k3_accum_init(const float* __restrict__ h, const float* __restrict__ deg,
                              const float* __restrict__ bp, const float* __restrict__ bs,
                              const float* __restrict__ bv, float* __restrict__ accum)
{
    int i = blockIdx.x * blockDim.x + threadIdx.x;
    if (i >= N_NODES) return;
#pragma unroll
    for (int s = 0; s < 3; ++s) {
        const float* b = (s == 0) ? bp : ((s == 1) ? bs : bv);
        float inv = 1.0f / deg[s * N_NODES + i];
#pragma unroll
        for (int c = 0; c < 5; ++c)
            accum[(s * N_NODES + i) * 5 + c] = h[(s * N_NODES + i) * 5 + c] * inv + b[c];
    }
}

__global__ void k4_scatter(const int* __restrict__ ep, const int* __restrict__ es,
                           const int* __restrict__ ev, const float* __restrict__ h,
                           const float* __restrict__ deg, float* __restrict__ accum)
{
    long e = (long)blockIdx.x * blockDim.x + threadIdx.x;
    if (e >= 3L * N_EDGES) return;
    int s = (int)(e / N_EDGES);
    int i = (int)(e - (long)s * N_EDGES);
    const int* ei = (s == 0) ? ep : ((s == 1) ? es : ev);
    int src = ei[i];
    int dst = ei[N_EDGES + i];
    float norm = rsqrtf(deg[s * N_NODES + src] * deg[s * N_NODES + dst]);
    const float* hp = h + (size_t)(s * N_NODES + src) * 5;
    float* ap = accum + (size_t)(s * N_NODES + dst) * 5;
#pragma unroll
    for (int c = 0; c < 5; ++c) atomicAdd(&ap[c], hp[c] * norm);
}

__global__ void k5_mlp(const float* __restrict__ accum,
                       const float* __restrict__ pw1, const float* __restrict__ pb1,
                       const float* __restrict__ pw2, const float* __restrict__ pb2,
                       const float* __restrict__ cw1, const float* __restrict__ cb1,
                       const float* __restrict__ cw2, const float* __restrict__ cb2,
                       float* __restrict__ out)
{
    __shared__ float sw[257];
    for (int j = threadIdx.x; j < 257; j += blockDim.x) {
        float v;
        if (j < 150) v = pw1[j];
        else if (j < 160) v = pb1[j - 150];
        else if (j < 210) v = pw2[j - 160];
        else if (j < 215) v = pb2[j - 210];
        else if (j < 240) v = cw1[j - 215];
        else if (j < 245) v = cb1[j - 240];
        else if (j < 255) v = cw2[j - 245];
        else v = cb2[j - 255];
        sw[j] = v;
    }
    __syncthreads();
    const float* W1 = sw; const float* B1 = sw + 150; const float* W2 = sw + 160;
    const float* B2 = sw + 210; const float* C1 = sw + 215; const float* D1 = sw + 240;
    const float* C2 = sw + 245; const float* D2 = sw + 255;
    int i = blockIdx.x * blockDim.x + threadIdx.x;
    if (i >= N_NODES) return;
    float hin[15];
#pragma unroll
    for (int s = 0; s < 3; ++s)
#pragma unroll
        for (int c = 0; c < 5; ++c)
            hin[s * 5 + c] = leaky_f(accum[(size_t)(s * N_NODES + i) * 5 + c]);
    float h1[10];
#pragma unroll
    for (int o = 0; o < 10; ++o) h1[o] = B1[o];
#pragma unroll
    for (int k = 0; k < 15; ++k)
#pragma unroll
        for (int o = 0; o < 10; ++o) h1[o] = fmaf(hin[k], W1[k * 10 + o], h1[o]);
#pragma unroll
    for (int o = 0; o < 10; ++o) h1[o] = leaky_f(h1[o]);
    float h2[5];
#pragma unroll
    for (int o = 0; o < 5; ++o) h2[o] = B2[o];
#pragma unroll
    for (int k = 0; k < 10; ++k)
#pragma unroll
        for (int o = 0; o < 5; ++o) h2[o] = fmaf(h1[k], W2[k * 5 + o], h2[o]);
    float h3[5];
#pragma unroll
    for (int o = 0; o < 5; ++o) h3[o] = D1[o];
#pragma unroll
    for (int k = 0; k < 5; ++k)
#pragma unroll
        for (int o = 0; o < 5; ++o) h3[o] = fmaf(h2[k], C1[k * 5 + o], h3[o]);
#pragma unroll
    for (int o = 0; o < 5; ++o) h3[o] = leaky_f(h3[o]);
    float o0 = D2[0], o1 = D2[1];
#pragma unroll
    for (int k = 0; k < 5; ++k) {
        o0 = fmaf(h3[k], C2[k * 2 + 0], o0);
        o1 = fmaf(h3[k], C2[k * 2 + 1], o1);
    }
    out[(size_t)i * 2 + 0] = o0;
    out[(size_t)i * 2 + 1] = o1;
}

// ===========================================================================

extern "C" void kernel_launch(void* const* d_in, const int* in_sizes, int n_in,
                              void* d_out, int out_size, void* d_ws, size_t ws_size,
                              hipStream_t stream)
{
    const float* x   = (const float*)d_in[0];
    const int*   ep  = (const int*)d_in[1];
    const int*   es  = (const int*)d_in[2];
    const int*   ev  = (const int*)d_in[3];
    const float* Wp  = (const float*)d_in[4];
    const float* bp  = (const float*)d_in[5];
    const float* Ws  = (const float*)d_in[6];
    const float* bs  = (const float*)d_in[7];
    const float* Wv  = (const float*)d_in[8];
    const float* bv  = (const float*)d_in[9];
    const float* pw1 = (const float*)d_in[10];
    const float* pb1 = (const float*)d_in[11];
    const float* pw2 = (const float*)d_in[12];
    const float* pb2 = (const float*)d_in[13];
    const float* cw1 = (const float*)d_in[14];
    const float* cb1 = (const float*)d_in[15];
    const float* cw2 = (const float*)d_in[16];
    const float* cb2 = (const float*)d_in[17];
    float* out = (float*)d_out;

    int gridN = (N_NODES + 255) / 256;

    const size_t H_BYTES    = 3ULL * N_NODES * 8 * 4;        // 48.0 MB
    const size_t P_BYTES    = 3ULL * N_EDGES * 4;            // 96.0 MB (parts)
    const size_t EA_BYTES   = 3ULL * N_EDGES * 4;            // 96.0 MB (eA; accum+G alias)
    const size_t ACC_BYTES  = 3ULL * NPAD * 5 * 4;           // 30.0 MB
    const size_t G_BYTES    = 3ULL * N_NODES * 16;           // 24.0 MB
    const size_t BHA_ELEMS  = 3ULL * NBKT * NRANGE;
    const size_t SEGT_ELEMS = 3ULL * NBKT * NSEGB;
    const size_t BHB_ELEMS  = 3ULL * NBKT * NBKT;
    const size_t META2      = (BHA_ELEMS + SEGT_ELEMS + BHB_ELEMS +
                               3 * NRANGE + 3 * (NRANGE + 1) +
                               3ULL * NSEGB * NBKT + 9ULL * NBKT) * 4 + 1024;
    const size_t NEED2 = H_BYTES + P_BYTES + EA_BYTES + META2;

    if (ws_size >= NEED2 && ACC_BYTES + G_BYTES <= EA_BYTES) {
        float* H      = (float*)d_ws;
        uint*  parts  = (uint*)((char*)d_ws + H_BYTES);
        uint*  eA     = parts + 3ULL * N_EDGES;
        float* accum  = (float*)eA;                       // alias: eA dead before p2a/p2b
        uint4* G      = (uint4*)((char*)eA + ACC_BYTES);  // alias: after accum, inside eA
        uint*  bhA    = eA + 3ULL * N_EDGES;
        uint*  segtotB = bhA + BHA_ELEMS;                 // uint4-aligned
        uint*  bhB    = segtotB + SEGT_ELEMS;
        uint*  colTotA = bhB + BHB_ELEMS;
        uint*  segA   = colTotA + 3 * NRANGE;
        uint*  segpreB = segA + 3 * (NRANGE + 1);
        uint*  countsB = segpreB + 3ULL * NSEGB * NBKT;
        uint*  baseB  = countsB + 3 * NBKT;
        uint*  bendB  = baseB + 3 * NBKT;

        dim3 gridP(NBKT, 3);
        dim3 gridCA(NRANGE, 3);
        dim3 gridB1((NBKT + 255) / 256, NSEGB, 3);
        dim3 gridB2((NBKT + 255) / 256, 3);

        k1_hx<<<gridN, 256, 0, stream>>>(x, Wp, Ws, Wv, H);
        pA_hist<<<gridP, CBLK, 0, stream>>>(ep, es, ev, bhA);
        colScanA<<<gridCA, 512, 0, stream>>>(bhA, colTotA);
        scanTotA<<<1, 64, 0, stream>>>(colTotA, segA);
        pA_scatter<<<gridP, CBLK, 0, stream>>>(ep, es, ev, bhA, segA, eA);
        pB_hist<<<gridP, CBLK, 0, stream>>>(eA, bhB);
        kB1_segscan<<<gridB1, 256, 0, stream>>>(bhB, segtotB);
        kB2_counts<<<gridB2, 256, 0, stream>>>(segtotB, countsB);
        scanB<<<3, 512, 0, stream>>>(countsB, baseB, bendB);
        kB3_segpre<<<gridB2, 256, 0, stream>>>(segtotB, baseB, segpreB);
        pB_scatter<<<gridP, CBLK, 0, stream>>>(eA, bhB, segpreB, segA, parts);
        p2a_deg2<<<gridP, 256, 0, stream>>>(parts, baseB, bendB, H, G);
        p2b_agg2<<<gridP, 512, 0, stream>>>(parts, baseB, bendB, H, G,
                                            bp, bs, bv, accum);
        k6_mlp<<<gridN, 256, 0, stream>>>(accum, pw1, pb1, pw2, pb2,
                                          cw1, cb1, cw2, cb2, out);
    } else {
        // minimal fallback (round-0 pipeline, needs 66 MB)
        float* ws    = (float*)d_ws;
        float* h     = ws;
        float* deg   = h + 3L * N_NODES * 5;
        float* accum = deg + 3L * N_NODES;

        const int BLK = 256;
        int gridNf = (N_NODES + BLK - 1) / BLK;
        long totalE = 3L * N_EDGES;
        int gridE = (int)((totalE + BLK - 1) / BLK);

        k1_gemm_deginit<<<gridNf, BLK, 0, stream>>>(x, Wp, Ws, Wv, h, deg);
        k2_degree<<<gridE, BLK, 0, stream>>>(ep, es, ev, deg);
        k3_accum_init<<<gridNf, BLK, 0, stream>>>(h, deg, bp, bs, bv, accum);
        k4_scatter<<<gridE, BLK, 0, stream>>>(ep, es, ev, h, deg, accum);
        k5_mlp<<<gridNf, BLK, 0, stream>>>(accum, pw1, pb1, pw2, pb2, cw1, cb1, cw2, cb2, out);
    }
}